// Round 2
// baseline (2087.193 us; speedup 1.0000x reference)
//
#include <hip/hip_runtime.h>
#include <hip/hip_fp16.h>

#define IC 1152   // input caps
#define IS 8      // input cap size
#define OC 10     // output caps
#define OS 16     // output cap size
#define OD 160    // OC*OS
#define SQ_EPS 1e-8f
#define NCH 9          // cap chunks per pass (1152 = 9 * 128)
#define CAPS_PER_CH 128

// -------------------------------------------------------------------------
// Kernel 1: u_hat[b,i,o] = sum_s x[b,i,s] * W[i,s,o], stored fp16.
// Block = (cap i, tile of 64 b). W[i] (5KB) + x tile (2KB) in LDS.
// Each thread computes 8 contiguous outputs -> one 16B store.
// -------------------------------------------------------------------------
__global__ __launch_bounds__(256) void uhat_kernel(
    const float* __restrict__ x, const float* __restrict__ W,
    __half* __restrict__ U, int Bn) {
  int i = blockIdx.x;
  int b0 = blockIdx.y * 64;
  __shared__ __align__(16) float Wl[IS][OD];
  __shared__ __align__(16) float xl[64][IS];
  int tid = threadIdx.x;

  for (int t = tid; t < IS * OD; t += 256)
    Wl[t / OD][t % OD] = W[(size_t)i * IS * OD + t];
  for (int t = tid; t < 64 * IS; t += 256) {
    int bb = t >> 3, s = t & 7;
    int b = b0 + bb;
    xl[bb][s] = (b < Bn) ? x[((size_t)b * IC + i) * IS + s] : 0.f;
  }
  __syncthreads();

  // 64 b * 20 octets = 1280 tasks, 5 per thread
  for (int a = tid; a < 64 * 20; a += 256) {
    int bb = a / 20, oc = a % 20;
    int b = b0 + bb;
    if (b >= Bn) continue;
    float acc[8] = {0, 0, 0, 0, 0, 0, 0, 0};
#pragma unroll
    for (int s = 0; s < 8; s++) {
      float xv = xl[bb][s];
      float4 w0 = *(const float4*)&Wl[s][oc * 8];
      float4 w1 = *(const float4*)&Wl[s][oc * 8 + 4];
      acc[0] += xv * w0.x; acc[1] += xv * w0.y;
      acc[2] += xv * w0.z; acc[3] += xv * w0.w;
      acc[4] += xv * w1.x; acc[5] += xv * w1.y;
      acc[6] += xv * w1.z; acc[7] += xv * w1.w;
    }
    union { __half2 h2[4]; uint4 u4; } pk;
#pragma unroll
    for (int k = 0; k < 4; k++)
      pk.h2[k] = __floats2half2_rn(acc[2 * k], acc[2 * k + 1]);
    *(uint4*)&U[((size_t)b * IC + i) * OD + oc * 8] = pk.u4;
  }
}

// -------------------------------------------------------------------------
// Kernel 2 (per pass): partial s_j over a 128-cap chunk for one b.
// logits = b_ij + u_hat . Vsum  (Vsum == 0 on pass 0 -> softmax(b_ij)).
// 256 threads: 4 lanes per cap (float4 d-slices), 64 caps/round, 2 rounds.
// Writes s_part[b][ch][160].
// -------------------------------------------------------------------------
template <bool PASS0>
__global__ __launch_bounds__(256) void pass_kernel(
    const __half* __restrict__ U, const float* __restrict__ bij,
    const float* __restrict__ Vsum, float* __restrict__ s_part) {
  int b = blockIdx.x;
  int ch = blockIdx.y;
  int tid = threadIdx.x;
  int wid = tid >> 6;
  int lane = tid & 63;
  int dq = lane & 3;                  // which float4 slice of d (0..3)
  int slot = wid * 16 + (lane >> 2);  // cap slot 0..63

  float4 vs[OC];
#pragma unroll
  for (int j = 0; j < OC; j++) {
    if (PASS0)
      vs[j] = make_float4(0.f, 0.f, 0.f, 0.f);
    else
      vs[j] = *(const float4*)&Vsum[(size_t)b * OD + j * 16 + dq * 4];
  }

  float4 sp[OC];
#pragma unroll
  for (int j = 0; j < OC; j++) sp[j] = make_float4(0.f, 0.f, 0.f, 0.f);

  for (int r = 0; r < CAPS_PER_CH / 64; ++r) {
    int cap = ch * CAPS_PER_CH + r * 64 + slot;
    const __half* up = U + ((size_t)b * IC + cap) * OD + dq * 4;
    float4 u[OC];
#pragma unroll
    for (int j = 0; j < OC; j++) {
      uint2 raw = *(const uint2*)(up + j * 16);
      float2 f0 = __half22float2(*(const __half2*)&raw.x);
      float2 f1 = __half22float2(*(const __half2*)&raw.y);
      u[j] = make_float4(f0.x, f0.y, f1.x, f1.y);
    }

    float l[OC];
#pragma unroll
    for (int j = 0; j < OC; j++) {
      float a = u[j].x * vs[j].x + u[j].y * vs[j].y + u[j].z * vs[j].z +
                u[j].w * vs[j].w;
      a += __shfl_xor(a, 1, 64);
      a += __shfl_xor(a, 2, 64);
      l[j] = bij[cap * OC + j] + a;
    }
    float m = l[0];
#pragma unroll
    for (int j = 1; j < OC; j++) m = fmaxf(m, l[j]);
    float sum = 0.f, c[OC];
#pragma unroll
    for (int j = 0; j < OC; j++) {
      c[j] = __expf(l[j] - m);
      sum += c[j];
    }
    float inv = 1.f / sum;
#pragma unroll
    for (int j = 0; j < OC; j++) {
      float cc = c[j] * inv;
      sp[j].x += cc * u[j].x;
      sp[j].y += cc * u[j].y;
      sp[j].z += cc * u[j].z;
      sp[j].w += cc * u[j].w;
    }
  }

  // butterfly reduce across the 16 cap slots of each wave (lane bits 2..5)
#pragma unroll
  for (int mask = 4; mask <= 32; mask <<= 1) {
#pragma unroll
    for (int j = 0; j < OC; j++) {
      sp[j].x += __shfl_xor(sp[j].x, mask, 64);
      sp[j].y += __shfl_xor(sp[j].y, mask, 64);
      sp[j].z += __shfl_xor(sp[j].z, mask, 64);
      sp[j].w += __shfl_xor(sp[j].w, mask, 64);
    }
  }

  __shared__ __align__(16) float sred[4][OD];
  if (lane < 4) {
#pragma unroll
    for (int j = 0; j < OC; j++)
      *(float4*)&sred[wid][j * 16 + dq * 4] = sp[j];
  }
  __syncthreads();

  if (tid < OD) {
    float s = sred[0][tid] + sred[1][tid] + sred[2][tid] + sred[3][tid];
    s_part[((size_t)b * NCH + ch) * OD + tid] = s;
  }
}

// -------------------------------------------------------------------------
// Kernel 3 (per pass): reduce 9 partials, squash, update Vsum / write out.
// mode: 0 = Vsum = v ; 1 = Vsum += v ; 2 = out = v (final)
// -------------------------------------------------------------------------
__global__ __launch_bounds__(192) void reduce_squash_kernel(
    const float* __restrict__ s_part, float* __restrict__ Vsum,
    float* __restrict__ out, int mode) {
  int b = blockIdx.x;
  int tid = threadIdx.x;
  __shared__ float sl[OD];
  __shared__ float sc[OC];

  if (tid < OD) {
    float s = 0.f;
#pragma unroll
    for (int chk = 0; chk < NCH; chk++)
      s += s_part[((size_t)b * NCH + chk) * OD + tid];
    sl[tid] = s;
  }
  __syncthreads();
  if (tid < OC) {
    float sq = 0.f;
#pragma unroll
    for (int d = 0; d < OS; d++) {
      float v = sl[tid * OS + d];
      sq += v * v;
    }
    sc[tid] = (sq / (1.f + sq)) / sqrtf(sq + SQ_EPS);
  }
  __syncthreads();
  if (tid < OD) {
    float v = sl[tid] * sc[tid >> 4];
    if (mode == 2)
      out[(size_t)b * OD + tid] = v;
    else if (mode == 0)
      Vsum[(size_t)b * OD + tid] = v;
    else
      Vsum[(size_t)b * OD + tid] += v;
  }
}

// -------------------------------------------------------------------------
// Fallback (ws too small): monolithic kernel recomputing u_hat from x,W.
// -------------------------------------------------------------------------
__global__ __launch_bounds__(256) void routing_fallback(
    const float* __restrict__ x, const float* __restrict__ W,
    const float* __restrict__ bij, float* __restrict__ out) {
  int b = blockIdx.x;
  int tid = threadIdx.x;
  int wid = tid >> 6;
  int lane = tid & 63;
  int dq = lane & 3;
  int slot = wid * 16 + (lane >> 2);

  __shared__ __align__(16) float Vs[OD];
  __shared__ __align__(16) float sred[4][OD];
  __shared__ float sc[OC];

  if (tid < OD) Vs[tid] = 0.f;
  __syncthreads();

  for (int pass = 0; pass < 4; ++pass) {
    float4 vs[OC];
#pragma unroll
    for (int j = 0; j < OC; j++) vs[j] = *(const float4*)&Vs[j * 16 + dq * 4];
    float4 sp[OC];
#pragma unroll
    for (int j = 0; j < OC; j++) sp[j] = make_float4(0.f, 0.f, 0.f, 0.f);

    for (int r = 0; r < IC / 64; ++r) {
      int cap = r * 64 + slot;
      float xr[8];
#pragma unroll
      for (int s = 0; s < 8; s++)
        xr[s] = x[((size_t)b * IC + cap) * IS + s];
      float4 u[OC];
#pragma unroll
      for (int j = 0; j < OC; j++) {
        float4 acc = make_float4(0.f, 0.f, 0.f, 0.f);
#pragma unroll
        for (int s = 0; s < 8; s++) {
          const float4 w =
              *(const float4*)&W[((size_t)cap * IS + s) * OD + j * 16 + dq * 4];
          acc.x += xr[s] * w.x;
          acc.y += xr[s] * w.y;
          acc.z += xr[s] * w.z;
          acc.w += xr[s] * w.w;
        }
        u[j] = acc;
      }
      float l[OC];
#pragma unroll
      for (int j = 0; j < OC; j++) {
        float a = u[j].x * vs[j].x + u[j].y * vs[j].y + u[j].z * vs[j].z +
                  u[j].w * vs[j].w;
        a += __shfl_xor(a, 1, 64);
        a += __shfl_xor(a, 2, 64);
        l[j] = bij[cap * OC + j] + a;
      }
      float m = l[0];
#pragma unroll
      for (int j = 1; j < OC; j++) m = fmaxf(m, l[j]);
      float sum = 0.f, c[OC];
#pragma unroll
      for (int j = 0; j < OC; j++) {
        c[j] = __expf(l[j] - m);
        sum += c[j];
      }
      float inv = 1.f / sum;
#pragma unroll
      for (int j = 0; j < OC; j++) {
        float cc = c[j] * inv;
        sp[j].x += cc * u[j].x;
        sp[j].y += cc * u[j].y;
        sp[j].z += cc * u[j].z;
        sp[j].w += cc * u[j].w;
      }
    }
#pragma unroll
    for (int mask = 4; mask <= 32; mask <<= 1) {
#pragma unroll
      for (int j = 0; j < OC; j++) {
        sp[j].x += __shfl_xor(sp[j].x, mask, 64);
        sp[j].y += __shfl_xor(sp[j].y, mask, 64);
        sp[j].z += __shfl_xor(sp[j].z, mask, 64);
        sp[j].w += __shfl_xor(sp[j].w, mask, 64);
      }
    }
    if (lane < 4) {
#pragma unroll
      for (int j = 0; j < OC; j++)
        *(float4*)&sred[wid][j * 16 + dq * 4] = sp[j];
    }
    __syncthreads();
    if (tid < OD) {
      float s = sred[0][tid] + sred[1][tid] + sred[2][tid] + sred[3][tid];
      sred[0][tid] = s;
    }
    __syncthreads();
    if (tid < OC) {
      float sq = 0.f;
#pragma unroll
      for (int d = 0; d < OS; d++) {
        float v = sred[0][tid * OS + d];
        sq += v * v;
      }
      sc[tid] = (sq / (1.f + sq)) / sqrtf(sq + SQ_EPS);
    }
    __syncthreads();
    if (tid < OD) {
      float vv = sred[0][tid] * sc[tid >> 4];
      if (pass < 3)
        Vs[tid] += vv;
      else
        out[(size_t)b * OD + tid] = vv;
    }
    __syncthreads();
  }
}

// -------------------------------------------------------------------------
extern "C" void kernel_launch(void* const* d_in, const int* in_sizes, int n_in,
                              void* d_out, int out_size, void* d_ws,
                              size_t ws_size, hipStream_t stream) {
  const float* x = (const float*)d_in[0];    // (B, 1152, 8)
  const float* W = (const float*)d_in[1];    // (1152, 8, 160)
  const float* bij = (const float*)d_in[2];  // (1152, 10)
  float* out = (float*)d_out;                // (B, 10, 16)

  int Bn = in_sizes[0] / (IC * IS);

  size_t u_bytes = (size_t)Bn * IC * OD * sizeof(__half);
  size_t spart_bytes = (size_t)Bn * NCH * OD * sizeof(float);
  size_t vsum_bytes = (size_t)Bn * OD * sizeof(float);

  if (ws_size >= u_bytes + spart_bytes + vsum_bytes) {
    __half* U = (__half*)d_ws;
    float* s_part = (float*)((char*)d_ws + u_bytes);
    float* Vsum = (float*)((char*)d_ws + u_bytes + spart_bytes);

    uhat_kernel<<<dim3(IC, (Bn + 63) / 64), 256, 0, stream>>>(x, W, U, Bn);

    dim3 pgrid(Bn, NCH);
    // pass 0: coupling = softmax(b_ij)  (Vsum treated as zero)
    pass_kernel<true><<<pgrid, 256, 0, stream>>>(U, bij, nullptr, s_part);
    reduce_squash_kernel<<<Bn, 192, 0, stream>>>(s_part, Vsum, out, 0);
    // routing iterations 1..3
    pass_kernel<false><<<pgrid, 256, 0, stream>>>(U, bij, Vsum, s_part);
    reduce_squash_kernel<<<Bn, 192, 0, stream>>>(s_part, Vsum, out, 1);
    pass_kernel<false><<<pgrid, 256, 0, stream>>>(U, bij, Vsum, s_part);
    reduce_squash_kernel<<<Bn, 192, 0, stream>>>(s_part, Vsum, out, 1);
    pass_kernel<false><<<pgrid, 256, 0, stream>>>(U, bij, Vsum, s_part);
    reduce_squash_kernel<<<Bn, 192, 0, stream>>>(s_part, Vsum, out, 2);
  } else {
    routing_fallback<<<Bn, 256, 0, stream>>>(x, W, bij, out);
  }
}

// Round 3
// 635.275 us; speedup vs baseline: 3.2855x; 3.2855x over previous
//
#include <hip/hip_runtime.h>

#define IC 1152   // input caps
#define IS 8      // input cap size
#define OC 10     // output caps
#define OS 16     // output cap size
#define OD 160    // OC*OS
#define SQ_EPS 1e-8f

// pass kernel geometry
#define BT 16               // batch elements per block
#define CPC 8               // caps per LDS chunk
#define CHUNKS 8            // chunks per block -> 64 caps per block
#define CG 18               // cap groups: 1152 / 64
#define WL_STRIDE 1296      // dwords per cap in LDS (1280 + 16 pad -> %32==16, 2-way free)
#define XL_STRIDE 68        // dwords per b row in LDS (64 + 4 pad)

// -------------------------------------------------------------------------
// Per-pass kernel: for a (16-b tile) x (64-cap group), recompute u_hat from
// x,W (W chunk staged fp32 in LDS), logits = bij + u.Vsum, softmax over j,
// accumulate partial s in registers, flush once via atomicAdd to s_accum.
// Threads: dq = tid&3 (float4 d-slice), ch = (tid>>2)&3 (cap stream),
//          bb = tid>>4 (batch element). All shuffles stay in-wave.
// -------------------------------------------------------------------------
template <bool PASS0>
__global__ __launch_bounds__(256) void pass_kernel(
    const float* __restrict__ x, const float* __restrict__ W,
    const float* __restrict__ bij, const float* __restrict__ Vsum,
    float* __restrict__ s_accum, int Bn) {
  int b0 = blockIdx.x * BT;
  int capg0 = blockIdx.y * (CPC * CHUNKS);
  int tid = threadIdx.x;
  int dq = tid & 3;
  int ch = (tid >> 2) & 3;
  int bb = tid >> 4;
  int b = b0 + bb;
  bool bok = b < Bn;

  __shared__ __align__(16) float Wl[CPC * WL_STRIDE];  // 41472 B
  __shared__ __align__(16) float xl[BT * XL_STRIDE];   // 4352 B
  __shared__ float bijl[CPC * CHUNKS * OC];            // 2560 B

  // stage bij for the whole 64-cap group (contiguous)
  for (int a = tid; a < CPC * CHUNKS * OC; a += 256)
    bijl[a] = bij[(size_t)capg0 * OC + a];

  // Vsum slice in registers (zero on pass 0)
  float4 vs[OC];
#pragma unroll
  for (int j = 0; j < OC; j++) {
    if (PASS0 || !bok)
      vs[j] = make_float4(0.f, 0.f, 0.f, 0.f);
    else
      vs[j] = *(const float4*)&Vsum[(size_t)b * OD + j * 16 + dq * 4];
  }

  float4 sacc[OC];
#pragma unroll
  for (int j = 0; j < OC; j++) sacc[j] = make_float4(0.f, 0.f, 0.f, 0.f);

  for (int c = 0; c < CHUNKS; ++c) {
    int cap0 = capg0 + c * CPC;
    __syncthreads();  // protect previous chunk's Wl/xl
    // stage W chunk: 8 caps * 1280 floats, float4-coalesced
#pragma unroll
    for (int k = 0; k < 10; k++) {
      int a4 = k * 256 + tid;  // 0..2559 float4s
      int ci = a4 / 320;
      int r4 = a4 - ci * 320;
      float4 w = *(const float4*)&W[(size_t)cap0 * 1280 + (size_t)a4 * 4];
      *(float4*)&Wl[ci * WL_STRIDE + r4 * 4] = w;
    }
    // stage x tile: 16 b * (8 caps * 8 s) floats
#pragma unroll
    for (int k = 0; k < 4; k++) {
      int a = k * 256 + tid;  // 0..1023
      int xb = a >> 6, r = a & 63;
      int gb = b0 + xb;
      xl[xb * XL_STRIDE + r] =
          (gb < Bn) ? x[((size_t)gb * IC + cap0) * IS + r] : 0.f;
    }
    __syncthreads();

#pragma unroll
    for (int it = 0; it < 2; ++it) {
      int ci = it * 4 + ch;
      int cap = cap0 + ci;
      float xf[8];
      *(float4*)&xf[0] = *(const float4*)&xl[bb * XL_STRIDE + ci * 8];
      *(float4*)&xf[4] = *(const float4*)&xl[bb * XL_STRIDE + ci * 8 + 4];

      float4 u[OC];
#pragma unroll
      for (int j = 0; j < OC; j++) {
        float4 acc = make_float4(0.f, 0.f, 0.f, 0.f);
#pragma unroll
        for (int s = 0; s < 8; s++) {
          float4 w = *(const float4*)&Wl[ci * WL_STRIDE + s * OD + j * 16 + dq * 4];
          acc.x += xf[s] * w.x;
          acc.y += xf[s] * w.y;
          acc.z += xf[s] * w.z;
          acc.w += xf[s] * w.w;
        }
        u[j] = acc;
      }

      float l[OC];
#pragma unroll
      for (int j = 0; j < OC; j++) {
        float a = u[j].x * vs[j].x + u[j].y * vs[j].y + u[j].z * vs[j].z +
                  u[j].w * vs[j].w;
        a += __shfl_xor(a, 1, 64);
        a += __shfl_xor(a, 2, 64);
        l[j] = bijl[(cap - capg0) * OC + j] + a;
      }
      float m = l[0];
#pragma unroll
      for (int j = 1; j < OC; j++) m = fmaxf(m, l[j]);
      float sum = 0.f, cc[OC];
#pragma unroll
      for (int j = 0; j < OC; j++) {
        cc[j] = __expf(l[j] - m);
        sum += cc[j];
      }
      float inv = 1.f / sum;
#pragma unroll
      for (int j = 0; j < OC; j++) {
        float w = cc[j] * inv;
        sacc[j].x += w * u[j].x;
        sacc[j].y += w * u[j].y;
        sacc[j].z += w * u[j].z;
        sacc[j].w += w * u[j].w;
      }
    }
  }

  // reduce the 4 cap streams (lane bits 2,3)
#pragma unroll
  for (int mask = 4; mask <= 8; mask <<= 1) {
#pragma unroll
    for (int j = 0; j < OC; j++) {
      sacc[j].x += __shfl_xor(sacc[j].x, mask, 64);
      sacc[j].y += __shfl_xor(sacc[j].y, mask, 64);
      sacc[j].z += __shfl_xor(sacc[j].z, mask, 64);
      sacc[j].w += __shfl_xor(sacc[j].w, mask, 64);
    }
  }
  if (ch == 0 && bok) {
    float* sb = s_accum + (size_t)b * OD + dq * 4;
#pragma unroll
    for (int j = 0; j < OC; j++) {
      atomicAdd(&sb[j * 16 + 0], sacc[j].x);
      atomicAdd(&sb[j * 16 + 1], sacc[j].y);
      atomicAdd(&sb[j * 16 + 2], sacc[j].z);
      atomicAdd(&sb[j * 16 + 3], sacc[j].w);
    }
  }
}

// -------------------------------------------------------------------------
// Reduce+squash: read s_accum[b], re-zero it for the next pass, squash,
// update Vsum (mode 0: =, mode 1: +=) or write the final output (mode 2).
// -------------------------------------------------------------------------
__global__ __launch_bounds__(192) void reduce_squash_kernel(
    float* __restrict__ s_accum, float* __restrict__ Vsum,
    float* __restrict__ out, int mode) {
  int b = blockIdx.x;
  int tid = threadIdx.x;
  __shared__ float sl[OD];
  __shared__ float sc[OC];
  if (tid < OD) {
    float s = s_accum[(size_t)b * OD + tid];
    s_accum[(size_t)b * OD + tid] = 0.f;  // re-zero for next pass
    sl[tid] = s;
  }
  __syncthreads();
  if (tid < OC) {
    float sq = 0.f;
#pragma unroll
    for (int d = 0; d < OS; d++) {
      float v = sl[tid * OS + d];
      sq += v * v;
    }
    sc[tid] = (sq / (1.f + sq)) / sqrtf(sq + SQ_EPS);
  }
  __syncthreads();
  if (tid < OD) {
    float v = sl[tid] * sc[tid >> 4];
    if (mode == 2)
      out[(size_t)b * OD + tid] = v;
    else if (mode == 0)
      Vsum[(size_t)b * OD + tid] = v;
    else
      Vsum[(size_t)b * OD + tid] += v;
  }
}

// -------------------------------------------------------------------------
// Fallback (ws tiny): monolithic per-b routing, fp32 recompute. Proven.
// -------------------------------------------------------------------------
__global__ __launch_bounds__(256) void routing_fallback(
    const float* __restrict__ x, const float* __restrict__ W,
    const float* __restrict__ bij, float* __restrict__ out) {
  int b = blockIdx.x;
  int tid = threadIdx.x;
  int wid = tid >> 6;
  int lane = tid & 63;
  int dq = lane & 3;
  int slot = wid * 16 + (lane >> 2);

  __shared__ __align__(16) float Vs[OD];
  __shared__ __align__(16) float sred[4][OD];
  __shared__ float sc[OC];

  if (tid < OD) Vs[tid] = 0.f;
  __syncthreads();

  for (int pass = 0; pass < 4; ++pass) {
    float4 vsr[OC];
#pragma unroll
    for (int j = 0; j < OC; j++) vsr[j] = *(const float4*)&Vs[j * 16 + dq * 4];
    float4 sp[OC];
#pragma unroll
    for (int j = 0; j < OC; j++) sp[j] = make_float4(0.f, 0.f, 0.f, 0.f);

    for (int r = 0; r < IC / 64; ++r) {
      int cap = r * 64 + slot;
      float xr[8];
#pragma unroll
      for (int s = 0; s < 8; s++) xr[s] = x[((size_t)b * IC + cap) * IS + s];
      float4 u[OC];
#pragma unroll
      for (int j = 0; j < OC; j++) {
        float4 acc = make_float4(0.f, 0.f, 0.f, 0.f);
#pragma unroll
        for (int s = 0; s < 8; s++) {
          const float4 w =
              *(const float4*)&W[((size_t)cap * IS + s) * OD + j * 16 + dq * 4];
          acc.x += xr[s] * w.x;
          acc.y += xr[s] * w.y;
          acc.z += xr[s] * w.z;
          acc.w += xr[s] * w.w;
        }
        u[j] = acc;
      }
      float l[OC];
#pragma unroll
      for (int j = 0; j < OC; j++) {
        float a = u[j].x * vsr[j].x + u[j].y * vsr[j].y + u[j].z * vsr[j].z +
                  u[j].w * vsr[j].w;
        a += __shfl_xor(a, 1, 64);
        a += __shfl_xor(a, 2, 64);
        l[j] = bij[cap * OC + j] + a;
      }
      float m = l[0];
#pragma unroll
      for (int j = 1; j < OC; j++) m = fmaxf(m, l[j]);
      float sum = 0.f, c[OC];
#pragma unroll
      for (int j = 0; j < OC; j++) {
        c[j] = __expf(l[j] - m);
        sum += c[j];
      }
      float inv = 1.f / sum;
#pragma unroll
      for (int j = 0; j < OC; j++) {
        float ccv = c[j] * inv;
        sp[j].x += ccv * u[j].x;
        sp[j].y += ccv * u[j].y;
        sp[j].z += ccv * u[j].z;
        sp[j].w += ccv * u[j].w;
      }
    }
#pragma unroll
    for (int mask = 4; mask <= 32; mask <<= 1) {
#pragma unroll
      for (int j = 0; j < OC; j++) {
        sp[j].x += __shfl_xor(sp[j].x, mask, 64);
        sp[j].y += __shfl_xor(sp[j].y, mask, 64);
        sp[j].z += __shfl_xor(sp[j].z, mask, 64);
        sp[j].w += __shfl_xor(sp[j].w, mask, 64);
      }
    }
    if (lane < 4) {
#pragma unroll
      for (int j = 0; j < OC; j++)
        *(float4*)&sred[wid][j * 16 + dq * 4] = sp[j];
    }
    __syncthreads();
    if (tid < OD) {
      float s = sred[0][tid] + sred[1][tid] + sred[2][tid] + sred[3][tid];
      sred[0][tid] = s;
    }
    __syncthreads();
    if (tid < OC) {
      float sq = 0.f;
#pragma unroll
      for (int d = 0; d < OS; d++) {
        float v = sred[0][tid * OS + d];
        sq += v * v;
      }
      sc[tid] = (sq / (1.f + sq)) / sqrtf(sq + SQ_EPS);
    }
    __syncthreads();
    if (tid < OD) {
      float vv = sred[0][tid] * sc[tid >> 4];
      if (pass < 3)
        Vs[tid] += vv;
      else
        out[(size_t)b * OD + tid] = vv;
    }
    __syncthreads();
  }
}

// -------------------------------------------------------------------------
extern "C" void kernel_launch(void* const* d_in, const int* in_sizes, int n_in,
                              void* d_out, int out_size, void* d_ws,
                              size_t ws_size, hipStream_t stream) {
  const float* x = (const float*)d_in[0];    // (B, 1152, 8)
  const float* W = (const float*)d_in[1];    // (1152, 8, 160)
  const float* bij = (const float*)d_in[2];  // (1152, 10)
  float* out = (float*)d_out;                // (B, 10, 16)

  int Bn = in_sizes[0] / (IC * IS);
  size_t buf = (size_t)Bn * OD * sizeof(float);

  float* s_accum = nullptr;
  float* Vs = nullptr;
  if (ws_size >= 2 * buf) {
    s_accum = (float*)d_ws;
    Vs = (float*)((char*)d_ws + buf);
  } else if (ws_size >= buf) {
    s_accum = (float*)d_ws;
    Vs = out;  // scribble on d_out between passes; final pass overwrites it
  } else {
    routing_fallback<<<Bn, 256, 0, stream>>>(x, W, bij, out);
    return;
  }

  hipMemsetAsync(s_accum, 0, buf, stream);

  dim3 pg((Bn + BT - 1) / BT, CG);
  pass_kernel<true><<<pg, 256, 0, stream>>>(x, W, bij, nullptr, s_accum, Bn);
  reduce_squash_kernel<<<Bn, 192, 0, stream>>>(s_accum, Vs, out, 0);
  pass_kernel<false><<<pg, 256, 0, stream>>>(x, W, bij, Vs, s_accum, Bn);
  reduce_squash_kernel<<<Bn, 192, 0, stream>>>(s_accum, Vs, out, 1);
  pass_kernel<false><<<pg, 256, 0, stream>>>(x, W, bij, Vs, s_accum, Bn);
  reduce_squash_kernel<<<Bn, 192, 0, stream>>>(s_accum, Vs, out, 1);
  pass_kernel<false><<<pg, 256, 0, stream>>>(x, W, bij, Vs, s_accum, Bn);
  reduce_squash_kernel<<<Bn, 192, 0, stream>>>(s_accum, Vs, out, 2);
}

// Round 4
// 262.786 us; speedup vs baseline: 7.9426x; 2.4175x over previous
//
#include <hip/hip_runtime.h>

#define IC 1152   // input caps
#define IS 8      // input cap size
#define OC 10     // output caps
#define OS 16     // output cap size
#define OD 160    // OC*OS
#define SQ_EPS 1e-8f

typedef _Float16 half8 __attribute__((ext_vector_type(8)));
typedef float f32x4 __attribute__((ext_vector_type(4)));

// =========================================================================
// MFMA path
// =========================================================================

// prep_w: WF fragment layout for A-operand of mfma_f32_16x16x32_f16.
// A[row=o (l&15)][k=(l>>4)*8+i] -> lanes 0..15 hold W[cap][i][j*16+o], i=0..7.
// Stored compact: WF[cap][j][l'=0..15][8 halves] (16B per lane).
__global__ __launch_bounds__(160) void prep_w(const float* __restrict__ W,
                                              uint4* __restrict__ WF) {
  int cap = blockIdx.x;
  int j = threadIdx.x >> 4;
  int lp = threadIdx.x & 15;
  union { _Float16 h[8]; uint4 u; } pk;
#pragma unroll
  for (int i = 0; i < 8; i++)
    pk.h[i] = (_Float16)W[(size_t)cap * (IS * OD) + i * OD + j * 16 + lp];
  WF[((size_t)cap * OC + j) * 16 + lp] = pk.u;
}

// pass_mfma: block = 16 b's x 64 caps (4 waves x 16 caps).
// Per cap: uT(16o x 16b) = mfma(WF-frag, x-frag); logits via in-reg dot +
// 2 shuffles; softmax per lane; weighted accumulate; LDS reduce; atomicAdd.
template <bool PASS0>
__global__ __launch_bounds__(256) void pass_mfma(
    const float* __restrict__ x, const uint4* __restrict__ WF,
    const float* __restrict__ bij, const float* __restrict__ Vsum,
    float* __restrict__ s_accum, int Bn) {
  int b0 = blockIdx.x * 16;
  int cap0 = blockIdx.y * 64;
  int tid = threadIdx.x;
  int wid = tid >> 6;
  int lane = tid & 63;
  int bl = lane & 15;       // b column this lane owns
  int og = (lane >> 4) * 4; // o-quad base for this lane's C rows
  int gb = b0 + bl;
  bool bok = gb < Bn;

  __shared__ __align__(16) uint4 xlh[64 * 16];       // 16 KB, f16-packed x
  __shared__ float sred[4 * 16 * 161];               // 41.2 KB

  // ---- stage x tile as packed f16, XOR-swizzled on the b index ----
  for (int e = tid; e < 64 * 16; e += 256) {
    int cc = e & 63, bb = e >> 6;
    int b = b0 + bb;
    float xf[8] = {0, 0, 0, 0, 0, 0, 0, 0};
    if (b < Bn) {
      *(float4*)&xf[0] = *(const float4*)&x[((size_t)b * IC + cap0 + cc) * IS];
      *(float4*)&xf[4] =
          *(const float4*)&x[((size_t)b * IC + cap0 + cc) * IS + 4];
    }
    union { _Float16 h[8]; uint4 u; } pk;
#pragma unroll
    for (int s = 0; s < 8; s++) pk.h[s] = (_Float16)xf[s];
    xlh[cc * 16 + (bb ^ (cc & 15))] = pk.u;
  }
  __syncthreads();

  // ---- Vsum slice for this lane: vs4[j] = Vsum[gb][j*16+og .. +4) ----
  f32x4 vs4[OC];
#pragma unroll
  for (int j = 0; j < OC; j++) vs4[j] = (f32x4){0.f, 0.f, 0.f, 0.f};
  if (!PASS0 && bok) {
    const float* vrow = Vsum + (size_t)gb * OD;
#pragma unroll
    for (int j = 0; j < OC; j++) {
      float4 t = *(const float4*)(vrow + j * 16 + og);
      vs4[j] = (f32x4){t.x, t.y, t.z, t.w};
    }
  }

  f32x4 sacc[OC];
#pragma unroll
  for (int j = 0; j < OC; j++) sacc[j] = (f32x4){0.f, 0.f, 0.f, 0.f};

  for (int c = 0; c < 16; ++c) {
    int cc = wid * 16 + c;   // cap-local, wave-uniform
    int cap = cap0 + cc;

    // B-operand (x): lanes 0..15 real, others broadcast addr 0 then zeroed
    union { uint4 u; half8 h; } xb;
    xb.u = xlh[cc * 16 + ((lane < 16 ? lane : 0) ^ (cc & 15))];
    if (lane >= 16) xb.u = make_uint4(0, 0, 0, 0);

    // 10 MFMAs: uT_j = WjT * xT
    f32x4 uf[OC];
#pragma unroll
    for (int j = 0; j < OC; j++) {
      union { uint4 u; half8 h; } wa;
      wa.u = WF[((size_t)cap * OC + j) * 16 + (lane & 15)];
      if (lane >= 16) wa.u = make_uint4(0, 0, 0, 0);
      f32x4 z = {0.f, 0.f, 0.f, 0.f};
      uf[j] = __builtin_amdgcn_mfma_f32_16x16x32_f16(wa.h, xb.h, z, 0, 0, 0);
    }

    // logits
    float l[OC];
#pragma unroll
    for (int j = 0; j < OC; j++) {
      float bj = bij[cap * OC + j];  // wave-uniform -> scalar load
      if (PASS0) {
        l[j] = bj;
      } else {
        float t = uf[j].x * vs4[j].x + uf[j].y * vs4[j].y +
                  uf[j].z * vs4[j].z + uf[j].w * vs4[j].w;
        t += __shfl_xor(t, 16, 64);
        t += __shfl_xor(t, 32, 64);
        l[j] = bj + t;
      }
    }
    // softmax over j (per lane; all lanes hold full logit row for their b)
    float m = l[0];
#pragma unroll
    for (int j = 1; j < OC; j++) m = fmaxf(m, l[j]);
    float sum = 0.f, cexp[OC];
#pragma unroll
    for (int j = 0; j < OC; j++) {
      cexp[j] = __expf(l[j] - m);
      sum += cexp[j];
    }
    float inv = 1.f / sum;
#pragma unroll
    for (int j = 0; j < OC; j++) {
      float cj = cexp[j] * inv;
      sacc[j].x += cj * uf[j].x;
      sacc[j].y += cj * uf[j].y;
      sacc[j].z += cj * uf[j].z;
      sacc[j].w += cj * uf[j].w;
    }
  }

  // ---- flush: lane writes s[b=bl][o=og+r] for each j ----
  float* sw = &sred[wid * (16 * 161) + bl * 161];
#pragma unroll
  for (int j = 0; j < OC; j++) {
    sw[j * 16 + og + 0] = sacc[j].x;
    sw[j * 16 + og + 1] = sacc[j].y;
    sw[j * 16 + og + 2] = sacc[j].z;
    sw[j * 16 + og + 3] = sacc[j].w;
  }
  __syncthreads();

  for (int e = tid; e < 16 * OD; e += 256) {
    int bb = e / OD, d = e - bb * OD;
    float s = sred[0 * (16 * 161) + bb * 161 + d] +
              sred[1 * (16 * 161) + bb * 161 + d] +
              sred[2 * (16 * 161) + bb * 161 + d] +
              sred[3 * (16 * 161) + bb * 161 + d];
    int g = b0 + bb;
    if (g < Bn) atomicAdd(&s_accum[(size_t)g * OD + d], s);
  }
}

// =========================================================================
// Reduce+squash (shared by MFMA and round-3 paths)
// mode: 0 = Vsum = v ; 1 = Vsum += v ; 2 = out = v (final)
// =========================================================================
__global__ __launch_bounds__(192) void reduce_squash_kernel(
    float* __restrict__ s_accum, float* __restrict__ Vsum,
    float* __restrict__ out, int mode) {
  int b = blockIdx.x;
  int tid = threadIdx.x;
  __shared__ float sl[OD];
  __shared__ float sc[OC];
  if (tid < OD) {
    float s = s_accum[(size_t)b * OD + tid];
    s_accum[(size_t)b * OD + tid] = 0.f;  // re-zero for next pass
    sl[tid] = s;
  }
  __syncthreads();
  if (tid < OC) {
    float sq = 0.f;
#pragma unroll
    for (int d = 0; d < OS; d++) {
      float v = sl[tid * OS + d];
      sq += v * v;
    }
    sc[tid] = (sq / (1.f + sq)) / sqrtf(sq + SQ_EPS);
  }
  __syncthreads();
  if (tid < OD) {
    float v = sl[tid] * sc[tid >> 4];
    if (mode == 2)
      out[(size_t)b * OD + tid] = v;
    else if (mode == 0)
      Vsum[(size_t)b * OD + tid] = v;
    else
      Vsum[(size_t)b * OD + tid] += v;
  }
}

// =========================================================================
// Round-3 VALU pass kernel (fallback tier, proven at 635us)
// =========================================================================
#define BT 16
#define CPC 8
#define CHUNKS 8
#define CG 18
#define WL_STRIDE 1296
#define XL_STRIDE 68

template <bool PASS0>
__global__ __launch_bounds__(256) void pass_kernel(
    const float* __restrict__ x, const float* __restrict__ W,
    const float* __restrict__ bij, const float* __restrict__ Vsum,
    float* __restrict__ s_accum, int Bn) {
  int b0 = blockIdx.x * BT;
  int capg0 = blockIdx.y * (CPC * CHUNKS);
  int tid = threadIdx.x;
  int dq = tid & 3;
  int ch = (tid >> 2) & 3;
  int bb = tid >> 4;
  int b = b0 + bb;
  bool bok = b < Bn;

  __shared__ __align__(16) float Wl[CPC * WL_STRIDE];
  __shared__ __align__(16) float xl[BT * XL_STRIDE];
  __shared__ float bijl[CPC * CHUNKS * OC];

  for (int a = tid; a < CPC * CHUNKS * OC; a += 256)
    bijl[a] = bij[(size_t)capg0 * OC + a];

  float4 vs[OC];
#pragma unroll
  for (int j = 0; j < OC; j++) {
    if (PASS0 || !bok)
      vs[j] = make_float4(0.f, 0.f, 0.f, 0.f);
    else
      vs[j] = *(const float4*)&Vsum[(size_t)b * OD + j * 16 + dq * 4];
  }

  float4 sacc[OC];
#pragma unroll
  for (int j = 0; j < OC; j++) sacc[j] = make_float4(0.f, 0.f, 0.f, 0.f);

  for (int c = 0; c < CHUNKS; ++c) {
    int cap0 = capg0 + c * CPC;
    __syncthreads();
#pragma unroll
    for (int k = 0; k < 10; k++) {
      int a4 = k * 256 + tid;
      int ci = a4 / 320;
      int r4 = a4 - ci * 320;
      float4 w = *(const float4*)&W[(size_t)cap0 * 1280 + (size_t)a4 * 4];
      *(float4*)&Wl[ci * WL_STRIDE + r4 * 4] = w;
    }
#pragma unroll
    for (int k = 0; k < 4; k++) {
      int a = k * 256 + tid;
      int xb = a >> 6, r = a & 63;
      int gbx = b0 + xb;
      xl[xb * XL_STRIDE + r] =
          (gbx < Bn) ? x[((size_t)gbx * IC + cap0) * IS + r] : 0.f;
    }
    __syncthreads();

#pragma unroll
    for (int it = 0; it < 2; ++it) {
      int ci = it * 4 + ch;
      int cap = cap0 + ci;
      float xf[8];
      *(float4*)&xf[0] = *(const float4*)&xl[bb * XL_STRIDE + ci * 8];
      *(float4*)&xf[4] = *(const float4*)&xl[bb * XL_STRIDE + ci * 8 + 4];

      float4 u[OC];
#pragma unroll
      for (int j = 0; j < OC; j++) {
        float4 acc = make_float4(0.f, 0.f, 0.f, 0.f);
#pragma unroll
        for (int s = 0; s < 8; s++) {
          float4 w =
              *(const float4*)&Wl[ci * WL_STRIDE + s * OD + j * 16 + dq * 4];
          acc.x += xf[s] * w.x;
          acc.y += xf[s] * w.y;
          acc.z += xf[s] * w.z;
          acc.w += xf[s] * w.w;
        }
        u[j] = acc;
      }

      float l[OC];
#pragma unroll
      for (int j = 0; j < OC; j++) {
        float a = u[j].x * vs[j].x + u[j].y * vs[j].y + u[j].z * vs[j].z +
                  u[j].w * vs[j].w;
        a += __shfl_xor(a, 1, 64);
        a += __shfl_xor(a, 2, 64);
        l[j] = bijl[(cap - capg0) * OC + j] + a;
      }
      float m = l[0];
#pragma unroll
      for (int j = 1; j < OC; j++) m = fmaxf(m, l[j]);
      float sum = 0.f, cc2[OC];
#pragma unroll
      for (int j = 0; j < OC; j++) {
        cc2[j] = __expf(l[j] - m);
        sum += cc2[j];
      }
      float inv = 1.f / sum;
#pragma unroll
      for (int j = 0; j < OC; j++) {
        float w = cc2[j] * inv;
        sacc[j].x += w * u[j].x;
        sacc[j].y += w * u[j].y;
        sacc[j].z += w * u[j].z;
        sacc[j].w += w * u[j].w;
      }
    }
  }

#pragma unroll
  for (int mask = 4; mask <= 8; mask <<= 1) {
#pragma unroll
    for (int j = 0; j < OC; j++) {
      sacc[j].x += __shfl_xor(sacc[j].x, mask, 64);
      sacc[j].y += __shfl_xor(sacc[j].y, mask, 64);
      sacc[j].z += __shfl_xor(sacc[j].z, mask, 64);
      sacc[j].w += __shfl_xor(sacc[j].w, mask, 64);
    }
  }
  if (ch == 0 && bok) {
    float* sb = s_accum + (size_t)b * OD + dq * 4;
#pragma unroll
    for (int j = 0; j < OC; j++) {
      atomicAdd(&sb[j * 16 + 0], sacc[j].x);
      atomicAdd(&sb[j * 16 + 1], sacc[j].y);
      atomicAdd(&sb[j * 16 + 2], sacc[j].z);
      atomicAdd(&sb[j * 16 + 3], sacc[j].w);
    }
  }
}

// =========================================================================
// Monolithic fallback (tiny ws)
// =========================================================================
__global__ __launch_bounds__(256) void routing_fallback(
    const float* __restrict__ x, const float* __restrict__ W,
    const float* __restrict__ bij, float* __restrict__ out) {
  int b = blockIdx.x;
  int tid = threadIdx.x;
  int wid = tid >> 6;
  int lane = tid & 63;
  int dq = lane & 3;
  int slot = wid * 16 + (lane >> 2);

  __shared__ __align__(16) float Vs[OD];
  __shared__ __align__(16) float sred2[4][OD];
  __shared__ float sc[OC];

  if (tid < OD) Vs[tid] = 0.f;
  __syncthreads();

  for (int pass = 0; pass < 4; ++pass) {
    float4 vsr[OC];
#pragma unroll
    for (int j = 0; j < OC; j++) vsr[j] = *(const float4*)&Vs[j * 16 + dq * 4];
    float4 sp[OC];
#pragma unroll
    for (int j = 0; j < OC; j++) sp[j] = make_float4(0.f, 0.f, 0.f, 0.f);

    for (int r = 0; r < IC / 64; ++r) {
      int cap = r * 64 + slot;
      float xr[8];
#pragma unroll
      for (int s = 0; s < 8; s++) xr[s] = x[((size_t)b * IC + cap) * IS + s];
      float4 u[OC];
#pragma unroll
      for (int j = 0; j < OC; j++) {
        float4 acc = make_float4(0.f, 0.f, 0.f, 0.f);
#pragma unroll
        for (int s = 0; s < 8; s++) {
          const float4 w =
              *(const float4*)&W[((size_t)cap * IS + s) * OD + j * 16 + dq * 4];
          acc.x += xr[s] * w.x;
          acc.y += xr[s] * w.y;
          acc.z += xr[s] * w.z;
          acc.w += xr[s] * w.w;
        }
        u[j] = acc;
      }
      float l[OC];
#pragma unroll
      for (int j = 0; j < OC; j++) {
        float a = u[j].x * vsr[j].x + u[j].y * vsr[j].y + u[j].z * vsr[j].z +
                  u[j].w * vsr[j].w;
        a += __shfl_xor(a, 1, 64);
        a += __shfl_xor(a, 2, 64);
        l[j] = bij[cap * OC + j] + a;
      }
      float m = l[0];
#pragma unroll
      for (int j = 1; j < OC; j++) m = fmaxf(m, l[j]);
      float sum = 0.f, c[OC];
#pragma unroll
      for (int j = 0; j < OC; j++) {
        c[j] = __expf(l[j] - m);
        sum += c[j];
      }
      float inv = 1.f / sum;
#pragma unroll
      for (int j = 0; j < OC; j++) {
        float ccv = c[j] * inv;
        sp[j].x += ccv * u[j].x;
        sp[j].y += ccv * u[j].y;
        sp[j].z += ccv * u[j].z;
        sp[j].w += ccv * u[j].w;
      }
    }
#pragma unroll
    for (int mask = 4; mask <= 32; mask <<= 1) {
#pragma unroll
      for (int j = 0; j < OC; j++) {
        sp[j].x += __shfl_xor(sp[j].x, mask, 64);
        sp[j].y += __shfl_xor(sp[j].y, mask, 64);
        sp[j].z += __shfl_xor(sp[j].z, mask, 64);
        sp[j].w += __shfl_xor(sp[j].w, mask, 64);
      }
    }
    if (lane < 4) {
#pragma unroll
      for (int j = 0; j < OC; j++)
        *(float4*)&sred2[wid][j * 16 + dq * 4] = sp[j];
    }
    __syncthreads();
    if (tid < OD) {
      float s = sred2[0][tid] + sred2[1][tid] + sred2[2][tid] + sred2[3][tid];
      sred2[0][tid] = s;
    }
    __syncthreads();
    if (tid < OC) {
      float sq = 0.f;
#pragma unroll
      for (int d = 0; d < OS; d++) {
        float v = sred2[0][tid * OS + d];
        sq += v * v;
      }
      sc[tid] = (sq / (1.f + sq)) / sqrtf(sq + SQ_EPS);
    }
    __syncthreads();
    if (tid < OD) {
      float vv = sred2[0][tid] * sc[tid >> 4];
      if (pass < 3)
        Vs[tid] += vv;
      else
        out[(size_t)b * OD + tid] = vv;
    }
    __syncthreads();
  }
}

// =========================================================================
extern "C" void kernel_launch(void* const* d_in, const int* in_sizes, int n_in,
                              void* d_out, int out_size, void* d_ws,
                              size_t ws_size, hipStream_t stream) {
  const float* x = (const float*)d_in[0];    // (B, 1152, 8)
  const float* W = (const float*)d_in[1];    // (1152, 8, 160)
  const float* bij = (const float*)d_in[2];  // (1152, 10)
  float* out = (float*)d_out;                // (B, 10, 16)

  int Bn = in_sizes[0] / (IC * IS);
  size_t buf = (size_t)Bn * OD * sizeof(float);
  size_t wf_bytes = (size_t)IC * OC * 16 * 16;  // 2.95 MB

  if (ws_size >= wf_bytes + 2 * buf) {
    // ---- MFMA path ----
    uint4* WF = (uint4*)d_ws;
    float* s_accum = (float*)((char*)d_ws + wf_bytes);
    float* Vs = (float*)((char*)d_ws + wf_bytes + buf);

    prep_w<<<IC, 160, 0, stream>>>(W, WF);
    hipMemsetAsync(s_accum, 0, buf, stream);

    dim3 pg((Bn + 15) / 16, IC / 64);
    pass_mfma<true><<<pg, 256, 0, stream>>>(x, WF, bij, nullptr, s_accum, Bn);
    reduce_squash_kernel<<<Bn, 192, 0, stream>>>(s_accum, Vs, out, 0);
    pass_mfma<false><<<pg, 256, 0, stream>>>(x, WF, bij, Vs, s_accum, Bn);
    reduce_squash_kernel<<<Bn, 192, 0, stream>>>(s_accum, Vs, out, 1);
    pass_mfma<false><<<pg, 256, 0, stream>>>(x, WF, bij, Vs, s_accum, Bn);
    reduce_squash_kernel<<<Bn, 192, 0, stream>>>(s_accum, Vs, out, 1);
    pass_mfma<false><<<pg, 256, 0, stream>>>(x, WF, bij, Vs, s_accum, Bn);
    reduce_squash_kernel<<<Bn, 192, 0, stream>>>(s_accum, Vs, out, 2);
  } else if (ws_size >= 2 * buf) {
    // ---- round-3 VALU path ----
    float* s_accum = (float*)d_ws;
    float* Vs = (float*)((char*)d_ws + buf);
    hipMemsetAsync(s_accum, 0, buf, stream);
    dim3 pg((Bn + BT - 1) / BT, CG);
    pass_kernel<true><<<pg, 256, 0, stream>>>(x, W, bij, nullptr, s_accum, Bn);
    reduce_squash_kernel<<<Bn, 192, 0, stream>>>(s_accum, Vs, out, 0);
    pass_kernel<false><<<pg, 256, 0, stream>>>(x, W, bij, Vs, s_accum, Bn);
    reduce_squash_kernel<<<Bn, 192, 0, stream>>>(s_accum, Vs, out, 1);
    pass_kernel<false><<<pg, 256, 0, stream>>>(x, W, bij, Vs, s_accum, Bn);
    reduce_squash_kernel<<<Bn, 192, 0, stream>>>(s_accum, Vs, out, 1);
    pass_kernel<false><<<pg, 256, 0, stream>>>(x, W, bij, Vs, s_accum, Bn);
    reduce_squash_kernel<<<Bn, 192, 0, stream>>>(s_accum, Vs, out, 2);
  } else {
    routing_fallback<<<Bn, 256, 0, stream>>>(x, W, bij, out);
  }
}